// Round 1
// baseline (413.813 us; speedup 1.0000x reference)
//
#include <hip/hip_runtime.h>

#define B_    32768
#define IN_   512
#define HID_  256
#define OUT_  128
#define E_    16
#define CTX_  256
#define DEMO_ 16
#define GIN_  784

typedef __attribute__((ext_vector_type(8))) short short8;   // 8 bf16 = 4 VGPRs
typedef __attribute__((ext_vector_type(4))) float floatx4;  // MFMA C/D

// fp32 -> bf16 with round-to-nearest-even
__device__ __forceinline__ short f2bf(float x){
  unsigned u = __builtin_bit_cast(unsigned, x);
  u += 0x7FFFu + ((u >> 16) & 1u);
  return (short)(u >> 16);
}

__device__ __forceinline__ void load_lds16(const short* g, short* l){
  __builtin_amdgcn_global_load_lds((const __attribute__((address_space(1))) void*)g,
                                   (__attribute__((address_space(3))) void*)l,
                                   16, 0, 0);
}

// Stage a 128x64 bf16 tile global->LDS with XOR-swizzle on the 16B column block.
// LDS[row][cb] = G[row][cb ^ (row&7)]  (cb = 16B-block index 0..7)
// Readers must fetch block (kb ^ (row&7)) to get logical block kb.
__device__ __forceinline__ void stage128x64(short* lds, const short* g, int gpitch, int tid){
  const int wvv = tid >> 6, ln = tid & 63;
  const int cb = ln & 7, rsub = ln >> 3;
  #pragma unroll
  for (int i = 0; i < 4; ++i){
    const int r0  = (wvv*4 + i)*8;           // wave-uniform row base
    const int row = r0 + rsub;
    const short* gp = g + (size_t)row*gpitch + ((cb ^ rsub) << 3);
    load_lds16(gp, lds + r0*64);             // lane writes base + lane*16B
  }
}

// ---------------- fp32 -> bf16 convert (x, W1, W2) ----------------
__global__ void convert_kernel(const float* __restrict__ x, const float* __restrict__ w1,
                               const float* __restrict__ w2, short* __restrict__ xb,
                               short* __restrict__ w1b, short* __restrict__ w2b){
  const int N1 = B_*IN_, N2 = E_*HID_*IN_, N3 = E_*OUT_*HID_;
  const int total4 = (N1 + N2 + N3) >> 2;
  for (int i = blockIdx.x*blockDim.x + threadIdx.x; i < total4; i += gridDim.x*blockDim.x){
    int e4 = i << 2;
    const float* src; short* dst; int off;
    if (e4 < N1)            { src = x;  dst = xb;  off = e4; }
    else if (e4 < N1 + N2)  { src = w1; dst = w1b; off = e4 - N1; }
    else                    { src = w2; dst = w2b; off = e4 - (N1 + N2); }
    float4 v = *(const float4*)(src + off);
    *(short4*)(dst + off) = make_short4(f2bf(v.x), f2bf(v.y), f2bf(v.z), f2bf(v.w));
  }
}

// ---------------- gate: softmax(cat(u,x,d) @ gW^T + gb) ----------------
// one wave per batch row
__global__ void gate_kernel(const float* __restrict__ u, const float* __restrict__ x,
                            const float* __restrict__ d, const float* __restrict__ gW,
                            const float* __restrict__ gb, float* __restrict__ wout){
  const int lane = threadIdx.x & 63;
  const int row  = blockIdx.x*4 + (threadIdx.x >> 6);
  float acc[E_];
  #pragma unroll
  for (int e = 0; e < E_; ++e) acc[e] = 0.f;
  #pragma unroll
  for (int t = 0; t < 12; ++t){
    const int i = t*64 + lane;                       // 0..767
    const float v = (t < 4) ? u[row*CTX_ + i] : x[row*IN_ + (i - 256)];
    #pragma unroll
    for (int e = 0; e < E_; ++e) acc[e] += v * gW[e*GIN_ + i];
  }
  if (lane < DEMO_){
    const float v = d[row*DEMO_ + lane];
    #pragma unroll
    for (int e = 0; e < E_; ++e) acc[e] += v * gW[e*GIN_ + 768 + lane];
  }
  #pragma unroll
  for (int e = 0; e < E_; ++e){
    #pragma unroll
    for (int m = 32; m >= 1; m >>= 1) acc[e] += __shfl_xor(acc[e], m);
  }
  if (lane == 0){
    float mx = -1e30f;
    #pragma unroll
    for (int e = 0; e < E_; ++e){ acc[e] += gb[e]; mx = fmaxf(mx, acc[e]); }
    float s = 0.f;
    #pragma unroll
    for (int e = 0; e < E_; ++e){ acc[e] = __expf(acc[e] - mx); s += acc[e]; }
    const float inv = 1.f / s;
    #pragma unroll
    for (int e = 0; e < E_; ++e) wout[row*E_ + e] = acc[e] * inv;
  }
}

// ---------------- fused MoE: per expert GEMM1 -> relu*gate -> GEMM2 accumulate ----------------
__global__ __launch_bounds__(256, 2)
void moe_kernel(const short* __restrict__ xb, const short* __restrict__ w1b,
                const short* __restrict__ w2b, const float* __restrict__ gatew,
                const float* __restrict__ b1g, const float* __restrict__ b2g,
                float* __restrict__ out){
  // LDS: 50 KB total. s_h (34816B) aliases s_x (16384B) - disjoint live ranges.
  __shared__ alignas(16) char smem[51200];
  short* s_x = (short*)smem;            // [128][64], GEMM1 A chunk (swizzled)
  short* s_h = (short*)smem;            // [128][136], H half-tile (padded, no swizzle)
  short* s_w = (short*)(smem + 34816);  // [128][64], W1/W2 chunk (swizzled)

  const int tid  = threadIdx.x;
  const int wv   = tid >> 6;
  const int lane = tid & 63;
  const int l15  = lane & 15;
  const int hi2  = lane >> 4;
  const int m_off = (wv >> 1) * 64;     // wave quadrant rows
  const int n_off = (wv & 1) * 64;      // wave quadrant cols
  const int blk_m0 = blockIdx.x * 128;
  const int eg = blockIdx.y;            // expert group 0/1

  floatx4 oacc[4][4];
  #pragma unroll
  for (int a = 0; a < 4; ++a)
    #pragma unroll
    for (int b = 0; b < 4; ++b) oacc[a][b] = floatx4{0.f, 0.f, 0.f, 0.f};

  // bias-2 term: out_init = sum_e w[b,e] * b2[e,o]  (done by eg==0 only)
  if (eg == 0){
    #pragma unroll 1
    for (int e = 0; e < E_; ++e){
      float b2v[4];
      #pragma unroll
      for (int nt = 0; nt < 4; ++nt) b2v[nt] = b2g[e*OUT_ + n_off + nt*16 + l15];
      #pragma unroll
      for (int mt = 0; mt < 4; ++mt){
        #pragma unroll
        for (int r = 0; r < 4; ++r){
          const float wgt = gatew[(blk_m0 + m_off + mt*16 + hi2*4 + r)*E_ + e];
          #pragma unroll
          for (int nt = 0; nt < 4; ++nt) oacc[mt][nt][r] += wgt * b2v[nt];
        }
      }
    }
  }

  #pragma unroll 1
  for (int ei = 0; ei < 8; ++ei){
    const int e = eg*8 + ei;
    #pragma unroll 1
    for (int half = 0; half < 2; ++half){
      // ---- GEMM1: H[128,128] = x[128,512] @ W1_e[half*128..+128, :]^T ----
      floatx4 g1[4][4];
      #pragma unroll
      for (int a = 0; a < 4; ++a)
        #pragma unroll
        for (int b = 0; b < 4; ++b) g1[a][b] = floatx4{0.f, 0.f, 0.f, 0.f};

      const short* w1base = w1b + (size_t)(e*HID_ + half*128) * IN_;
      #pragma unroll 1
      for (int kc = 0; kc < 8; ++kc){
        stage128x64(s_x, xb + (size_t)blk_m0*IN_ + kc*64, IN_, tid);
        stage128x64(s_w, w1base + kc*64, IN_, tid);
        __syncthreads();
        #pragma unroll
        for (int ks = 0; ks < 2; ++ks){
          const int kb = ks*4 + hi2;                 // logical 16B block 0..7
          const int sw = (kb ^ (l15 & 7)) << 3;      // swizzled element offset
          short8 af[4], bf[4];
          #pragma unroll
          for (int mt = 0; mt < 4; ++mt)
            af[mt] = *(const short8*)&s_x[(m_off + mt*16 + l15)*64 + sw];
          #pragma unroll
          for (int nt = 0; nt < 4; ++nt)
            bf[nt] = *(const short8*)&s_w[(n_off + nt*16 + l15)*64 + sw];
          #pragma unroll
          for (int mt = 0; mt < 4; ++mt)
            #pragma unroll
            for (int nt = 0; nt < 4; ++nt)
              g1[mt][nt] = __builtin_amdgcn_mfma_f32_16x16x32_bf16(af[mt], bf[nt], g1[mt][nt], 0, 0, 0);
        }
        __syncthreads();
      }

      // prefetch W2 chunk 0 (async into s_w) while epilogue writes s_h
      const short* w2base = w2b + (size_t)e*OUT_*HID_ + half*128;
      stage128x64(s_w, w2base, HID_, tid);

      // ---- epilogue: relu(+b1) * gate weight -> bf16 -> s_h (C-layout -> A-layout via LDS) ----
      {
        float b1v[4];
        #pragma unroll
        for (int nt = 0; nt < 4; ++nt)
          b1v[nt] = b1g[e*HID_ + half*128 + n_off + nt*16 + l15];
        #pragma unroll
        for (int mt = 0; mt < 4; ++mt){
          #pragma unroll
          for (int r = 0; r < 4; ++r){
            const int m = m_off + mt*16 + hi2*4 + r;
            const float wgt = gatew[(blk_m0 + m)*E_ + e];
            #pragma unroll
            for (int nt = 0; nt < 4; ++nt){
              float hv = g1[mt][nt][r] + b1v[nt];
              hv = fmaxf(hv, 0.f) * wgt;
              s_h[m*136 + n_off + nt*16 + l15] = f2bf(hv);
            }
          }
        }
      }
      __syncthreads();   // s_h ready AND W2 chunk0 staged

      // ---- GEMM2: oacc += H[128,128] @ W2_e[:, half*128..+128]^T ----
      #pragma unroll 1
      for (int kc2 = 0; kc2 < 2; ++kc2){
        #pragma unroll
        for (int ks = 0; ks < 2; ++ks){
          const int kb = ks*4 + hi2;
          const int kk = kc2*64 + (kb << 3);         // k within this half (0..127)
          const int sw = (kb ^ (l15 & 7)) << 3;
          short8 af[4], bf[4];
          #pragma unroll
          for (int mt = 0; mt < 4; ++mt)
            af[mt] = *(const short8*)&s_h[(m_off + mt*16 + l15)*136 + kk];
          #pragma unroll
          for (int nt = 0; nt < 4; ++nt)
            bf[nt] = *(const short8*)&s_w[(n_off + nt*16 + l15)*64 + sw];
          #pragma unroll
          for (int mt = 0; mt < 4; ++mt)
            #pragma unroll
            for (int nt = 0; nt < 4; ++nt)
              oacc[mt][nt] = __builtin_amdgcn_mfma_f32_16x16x32_bf16(af[mt], bf[nt], oacc[mt][nt], 0, 0, 0);
        }
        __syncthreads();                  // readers of s_w/s_h done
        if (kc2 == 0){
          stage128x64(s_w, w2base + 64, HID_, tid);  // W2 chunk 1
          __syncthreads();
        }
      }
    }
  }

  // ---- output: device-scope fp32 atomics (two expert-group blocks per tile) ----
  #pragma unroll
  for (int mt = 0; mt < 4; ++mt)
    #pragma unroll
    for (int nt = 0; nt < 4; ++nt)
      #pragma unroll
      for (int r = 0; r < 4; ++r)
        atomicAdd(&out[(size_t)(blk_m0 + m_off + mt*16 + hi2*4 + r)*OUT_ + n_off + nt*16 + l15],
                  oacc[mt][nt][r]);
}

extern "C" void kernel_launch(void* const* d_in, const int* in_sizes, int n_in,
                              void* d_out, int out_size, void* d_ws, size_t ws_size,
                              hipStream_t stream){
  const float* x  = (const float*)d_in[0];
  const float* u  = (const float*)d_in[1];
  const float* dd = (const float*)d_in[2];
  const float* gW = (const float*)d_in[3];
  const float* gb = (const float*)d_in[4];
  const float* W1 = (const float*)d_in[5];
  const float* b1 = (const float*)d_in[6];
  const float* W2 = (const float*)d_in[7];
  const float* b2 = (const float*)d_in[8];
  float* out = (float*)d_out;

  // workspace layout (bf16 copies + gate weights): ~40.9 MB
  short* xb  = (short*)d_ws;
  short* w1b = xb  + (size_t)B_*IN_;
  short* w2b = w1b + (size_t)E_*HID_*IN_;
  float* gw  = (float*)(w2b + (size_t)E_*OUT_*HID_);

  hipMemsetAsync(d_out, 0, (size_t)B_*OUT_*sizeof(float), stream);
  hipLaunchKernelGGL(convert_kernel, dim3(4096), dim3(256), 0, stream, x, W1, W2, xb, w1b, w2b);
  hipLaunchKernelGGL(gate_kernel, dim3(B_/4), dim3(256), 0, stream, u, x, dd, gW, gb, gw);
  hipLaunchKernelGGL(moe_kernel, dim3(B_/128, 2), dim3(256), 0, stream, xb, w1b, w2b, gw, b1, b2, out);
  (void)in_sizes; (void)n_in; (void)out_size; (void)ws_size;
}

// Round 2
// 383.421 us; speedup vs baseline: 1.0793x; 1.0793x over previous
//
#include <hip/hip_runtime.h>

#define B_    32768
#define IN_   512
#define HID_  256
#define OUT_  128
#define E_    16
#define CTX_  256
#define DEMO_ 16
#define GIN_  784

typedef __attribute__((ext_vector_type(8))) short short8;   // 8 bf16 = 4 VGPRs
typedef __attribute__((ext_vector_type(4))) float floatx4;  // MFMA C/D

// fp32 -> bf16 round-to-nearest-even
__device__ __forceinline__ short f2bf(float x){
  unsigned u = __builtin_bit_cast(unsigned, x);
  u += 0x7FFFu + ((u >> 16) & 1u);
  return (short)(u >> 16);
}

__device__ __forceinline__ short8 pack8(float4 a, float4 b){
  short8 r;
  r[0]=f2bf(a.x); r[1]=f2bf(a.y); r[2]=f2bf(a.z); r[3]=f2bf(a.w);
  r[4]=f2bf(b.x); r[5]=f2bf(b.y); r[6]=f2bf(b.z); r[7]=f2bf(b.w);
  return r;
}

__device__ __forceinline__ void load_lds16(const short* g, short* l){
  __builtin_amdgcn_global_load_lds((const __attribute__((address_space(1))) void*)g,
                                   (__attribute__((address_space(3))) void*)l,
                                   16, 0, 0);
}

// Stage a 128x64 bf16 tile global->LDS with XOR-swizzle on the 16B column block.
// LDS[row][cb] = G[row][cb ^ (row&7)]; readers fetch block (kb ^ (row&7)).
__device__ __forceinline__ void stage128x64(short* lds, const short* g, int gpitch, int tid){
  const int wvv = tid >> 6, ln = tid & 63;
  const int cb = ln & 7, rsub = ln >> 3;
  #pragma unroll
  for (int i = 0; i < 4; ++i){
    const int r0  = (wvv*4 + i)*8;           // wave-uniform row base
    const int row = r0 + rsub;
    const short* gp = g + (size_t)row*gpitch + ((cb ^ rsub) << 3);
    load_lds16(gp, lds + r0*64);             // lane writes base + lane*16B
  }
}

// ---------------- fp32 -> bf16 convert (x, W1, W2) ----------------
__global__ void convert_kernel(const float* __restrict__ x, const float* __restrict__ w1,
                               const float* __restrict__ w2, short* __restrict__ xb,
                               short* __restrict__ w1b, short* __restrict__ w2b){
  const int N1 = B_*IN_, N2 = E_*HID_*IN_, N3 = E_*OUT_*HID_;
  const int total4 = (N1 + N2 + N3) >> 2;
  for (int i = blockIdx.x*blockDim.x + threadIdx.x; i < total4; i += gridDim.x*blockDim.x){
    int e4 = i << 2;
    const float* src; short* dst; int off;
    if (e4 < N1)            { src = x;  dst = xb;  off = e4; }
    else if (e4 < N1 + N2)  { src = w1; dst = w1b; off = e4 - N1; }
    else                    { src = w2; dst = w2b; off = e4 - (N1 + N2); }
    float4 v = *(const float4*)(src + off);
    *(short4*)(dst + off) = make_short4(f2bf(v.x), f2bf(v.y), f2bf(v.z), f2bf(v.w));
  }
}

// ---------------- gate via MFMA: softmax(cat(u,x,d) @ gW^T + gb) ----------------
// one wave computes a 16-row x 16-expert logit tile; K segments: u 256, x 512, d 16
__global__ __launch_bounds__(256)
void gate_kernel(const float* __restrict__ u, const short* __restrict__ xb,
                 const float* __restrict__ d, const float* __restrict__ gW,
                 const float* __restrict__ gb, float* __restrict__ wout){
  const int tid  = threadIdx.x;
  const int wave = tid >> 6, lane = tid & 63;
  const int l15  = lane & 15, quad = lane >> 4;
  const int row0 = blockIdx.x*64 + wave*16;
  const int rA   = row0 + l15;                 // A-operand row for this lane
  const int kq   = quad*8;                     // k sub-offset within 32-wide step

  floatx4 acc  = {0.f,0.f,0.f,0.f};
  floatx4 acc2 = {0.f,0.f,0.f,0.f};

  // u segment (features 0..255)
  #pragma unroll
  for (int t = 0; t < 8; ++t){
    const float4 a0 = *(const float4*)&u[(size_t)rA*CTX_ + t*32 + kq];
    const float4 a1 = *(const float4*)&u[(size_t)rA*CTX_ + t*32 + kq + 4];
    const float4 b0 = *(const float4*)&gW[(size_t)l15*GIN_ + t*32 + kq];
    const float4 b1 = *(const float4*)&gW[(size_t)l15*GIN_ + t*32 + kq + 4];
    acc = __builtin_amdgcn_mfma_f32_16x16x32_bf16(pack8(a0,a1), pack8(b0,b1), acc, 0,0,0);
  }
  // x segment (features 256..767), bf16 input already converted
  #pragma unroll
  for (int t = 0; t < 16; ++t){
    const short8 af = *(const short8*)&xb[(size_t)rA*IN_ + t*32 + kq];
    const float4 b0 = *(const float4*)&gW[(size_t)l15*GIN_ + 256 + t*32 + kq];
    const float4 b1 = *(const float4*)&gW[(size_t)l15*GIN_ + 256 + t*32 + kq + 4];
    acc2 = __builtin_amdgcn_mfma_f32_16x16x32_bf16(af, pack8(b0,b1), acc2, 0,0,0);
  }
  // d segment (features 768..783): zero-pad K to 32, quads 2,3 contribute zeros
  {
    short8 af = {0,0,0,0,0,0,0,0}, bf = {0,0,0,0,0,0,0,0};
    if (quad < 2){
      const float4 a0 = *(const float4*)&d[(size_t)rA*DEMO_ + kq];
      const float4 a1 = *(const float4*)&d[(size_t)rA*DEMO_ + kq + 4];
      const float4 b0 = *(const float4*)&gW[(size_t)l15*GIN_ + 768 + kq];
      const float4 b1 = *(const float4*)&gW[(size_t)l15*GIN_ + 768 + kq + 4];
      af = pack8(a0,a1); bf = pack8(b0,b1);
    }
    acc = __builtin_amdgcn_mfma_f32_16x16x32_bf16(af, bf, acc, 0,0,0);
  }

  const float bias = gb[l15];
  #pragma unroll
  for (int r = 0; r < 4; ++r){
    float v = acc[r] + acc2[r] + bias;      // logits[row0+quad*4+r][e=l15]
    float m = v;
    #pragma unroll
    for (int s = 1; s <= 8; s <<= 1) m = fmaxf(m, __shfl_xor(m, s));
    const float p = __expf(v - m);
    float ssum = p;
    #pragma unroll
    for (int s = 1; s <= 8; s <<= 1) ssum += __shfl_xor(ssum, s);
    wout[(size_t)(row0 + quad*4 + r)*E_ + l15] = p / ssum;
  }
}

// ---------------- fused MoE ----------------
// GEMM1 computes H^T (A=W1 rows -> h, B=x rows -> m): lane holds 4 h-consecutive
// values => vectorized ds_write_b64 epilogue into s_h[m][h]; GEMM2 A-frags read
// s_h rows contiguously. Expert split 4-way for 3 blocks/CU residency.
__global__ __launch_bounds__(256, 2)
void moe_kernel(const short* __restrict__ xb, const short* __restrict__ w1b,
                const short* __restrict__ w2b, const float* __restrict__ gatew,
                const float* __restrict__ b1g, const float* __restrict__ b2g,
                float* __restrict__ out){
  // LDS 50 KB: s_h (34816B) aliases s_x+s_w1 (32768B) - disjoint live ranges.
  __shared__ alignas(16) char smem[51200];
  short* s_x  = (short*)smem;             // [128][64] GEMM1 B-operand (batch rows), swizzled
  short* s_w1 = (short*)(smem + 16384);   // [128][64] GEMM1 A-operand (W1 rows), swizzled
  short* s_h  = (short*)smem;             // [128][136] H[m][h] (pitch-padded, no swizzle)
  short* s_w2 = (short*)(smem + 34816);   // [128][64] W2 chunk, swizzled

  const int tid  = threadIdx.x;
  const int wv   = tid >> 6;
  const int lane = tid & 63;
  const int l15  = lane & 15;
  const int hi2  = lane >> 4;
  const int h_off  = (wv >> 1) * 64;      // GEMM1: A rows (hidden)
  const int mb_off = (wv & 1) * 64;       // GEMM1: B cols (batch)
  const int m_off  = (wv >> 1) * 64;      // GEMM2: rows (batch)
  const int o_off  = (wv & 1) * 64;       // GEMM2: cols (out)
  const int blk_m0 = blockIdx.x * 128;
  const int eg = blockIdx.y;              // expert group 0..3

  floatx4 oacc[4][4];
  #pragma unroll
  for (int a = 0; a < 4; ++a)
    #pragma unroll
    for (int b = 0; b < 4; ++b) oacc[a][b] = floatx4{0.f,0.f,0.f,0.f};

  // bias-2 term: out_init = sum_e w[b,e] * b2[e,o]  (eg==0 blocks only)
  if (eg == 0){
    #pragma unroll 1
    for (int e = 0; e < E_; ++e){
      float b2v[4];
      #pragma unroll
      for (int nt = 0; nt < 4; ++nt) b2v[nt] = b2g[e*OUT_ + o_off + nt*16 + l15];
      #pragma unroll
      for (int mt = 0; mt < 4; ++mt){
        #pragma unroll
        for (int r = 0; r < 4; ++r){
          const float wgt = gatew[(size_t)(blk_m0 + m_off + mt*16 + hi2*4 + r)*E_ + e];
          #pragma unroll
          for (int nt = 0; nt < 4; ++nt) oacc[mt][nt][r] += wgt * b2v[nt];
        }
      }
    }
  }

  #pragma unroll 1
  for (int ei = 0; ei < 4; ++ei){
    const int e = eg*4 + ei;
    #pragma unroll 1
    for (int half = 0; half < 2; ++half){
      // ---- GEMM1: H^T[128h,128m] = W1_e[half] @ x^T ----
      floatx4 g1[4][4];
      #pragma unroll
      for (int a = 0; a < 4; ++a)
        #pragma unroll
        for (int b = 0; b < 4; ++b) g1[a][b] = floatx4{0.f,0.f,0.f,0.f};

      const short* w1base = w1b + (size_t)(e*HID_ + half*128) * IN_;
      #pragma unroll 1
      for (int kc = 0; kc < 8; ++kc){
        stage128x64(s_x,  xb + (size_t)blk_m0*IN_ + kc*64, IN_, tid);
        stage128x64(s_w1, w1base + kc*64, IN_, tid);
        __syncthreads();
        #pragma unroll
        for (int ks = 0; ks < 2; ++ks){
          const int kb = ks*4 + hi2;
          const int sw = (kb ^ (l15 & 7)) << 3;
          short8 af[4], bf[4];
          #pragma unroll
          for (int ht = 0; ht < 4; ++ht)
            af[ht] = *(const short8*)&s_w1[(h_off + ht*16 + l15)*64 + sw];
          #pragma unroll
          for (int mt = 0; mt < 4; ++mt)
            bf[mt] = *(const short8*)&s_x[(mb_off + mt*16 + l15)*64 + sw];
          #pragma unroll
          for (int ht = 0; ht < 4; ++ht)
            #pragma unroll
            for (int mt = 0; mt < 4; ++mt)
              g1[ht][mt] = __builtin_amdgcn_mfma_f32_16x16x32_bf16(af[ht], bf[mt], g1[ht][mt], 0,0,0);
        }
        __syncthreads();
      }

      // prefetch W2 chunk 0 into s_w2 (disjoint from s_h) while epilogue runs
      const short* w2base = w2b + (size_t)e*OUT_*HID_ + half*128;
      stage128x64(s_w2, w2base, HID_, tid);

      // ---- epilogue: relu(+b1)*gate -> bf16, vectorized b64 writes to s_h[m][h] ----
      {
        float4 b1v[4];
        #pragma unroll
        for (int ht = 0; ht < 4; ++ht)
          b1v[ht] = *(const float4*)&b1g[e*HID_ + half*128 + h_off + ht*16 + hi2*4];
        float wgt[4];
        #pragma unroll
        for (int mt = 0; mt < 4; ++mt)
          wgt[mt] = gatew[(size_t)(blk_m0 + mb_off + mt*16 + l15)*E_ + e];
        #pragma unroll
        for (int ht = 0; ht < 4; ++ht){
          const float b1r[4] = {b1v[ht].x, b1v[ht].y, b1v[ht].z, b1v[ht].w};
          #pragma unroll
          for (int mt = 0; mt < 4; ++mt){
            short4 pk;
            float v0 = fmaxf(g1[ht][mt][0] + b1r[0], 0.f) * wgt[mt];
            float v1 = fmaxf(g1[ht][mt][1] + b1r[1], 0.f) * wgt[mt];
            float v2 = fmaxf(g1[ht][mt][2] + b1r[2], 0.f) * wgt[mt];
            float v3 = fmaxf(g1[ht][mt][3] + b1r[3], 0.f) * wgt[mt];
            pk.x = f2bf(v0); pk.y = f2bf(v1); pk.z = f2bf(v2); pk.w = f2bf(v3);
            *(short4*)&s_h[(size_t)(mb_off + mt*16 + l15)*136 + h_off + ht*16 + hi2*4] = pk;
          }
        }
      }
      __syncthreads();   // s_h ready AND W2 chunk0 staged

      // ---- GEMM2: oacc += H[128,128] @ W2_e[:,half]^T ----
      #pragma unroll 1
      for (int kc2 = 0; kc2 < 2; ++kc2){
        #pragma unroll
        for (int ks = 0; ks < 2; ++ks){
          const int kb = ks*4 + hi2;
          const int kk = kc2*64 + (kb << 3);
          const int sw = (kb ^ (l15 & 7)) << 3;
          short8 af[4], bf[4];
          #pragma unroll
          for (int mt = 0; mt < 4; ++mt)
            af[mt] = *(const short8*)&s_h[(m_off + mt*16 + l15)*136 + kk];
          #pragma unroll
          for (int nt = 0; nt < 4; ++nt)
            bf[nt] = *(const short8*)&s_w2[(o_off + nt*16 + l15)*64 + sw];
          #pragma unroll
          for (int mt = 0; mt < 4; ++mt)
            #pragma unroll
            for (int nt = 0; nt < 4; ++nt)
              oacc[mt][nt] = __builtin_amdgcn_mfma_f32_16x16x32_bf16(af[mt], bf[nt], oacc[mt][nt], 0,0,0);
        }
        __syncthreads();
        if (kc2 == 0){
          stage128x64(s_w2, w2base + 64, HID_, tid);   // W2 chunk 1
          __syncthreads();
        }
      }
    }
  }

  // ---- output: device-scope fp32 atomics (4 expert-group blocks per tile) ----
  #pragma unroll
  for (int mt = 0; mt < 4; ++mt)
    #pragma unroll
    for (int nt = 0; nt < 4; ++nt)
      #pragma unroll
      for (int r = 0; r < 4; ++r)
        atomicAdd(&out[(size_t)(blk_m0 + m_off + mt*16 + hi2*4 + r)*OUT_ + o_off + nt*16 + l15],
                  oacc[mt][nt][r]);
}

extern "C" void kernel_launch(void* const* d_in, const int* in_sizes, int n_in,
                              void* d_out, int out_size, void* d_ws, size_t ws_size,
                              hipStream_t stream){
  const float* x  = (const float*)d_in[0];
  const float* u  = (const float*)d_in[1];
  const float* dd = (const float*)d_in[2];
  const float* gW = (const float*)d_in[3];
  const float* gb = (const float*)d_in[4];
  const float* W1 = (const float*)d_in[5];
  const float* b1 = (const float*)d_in[6];
  const float* W2 = (const float*)d_in[7];
  const float* b2 = (const float*)d_in[8];
  float* out = (float*)d_out;

  short* xb  = (short*)d_ws;
  short* w1b = xb  + (size_t)B_*IN_;
  short* w2b = w1b + (size_t)E_*HID_*IN_;
  float* gw  = (float*)(w2b + (size_t)E_*OUT_*HID_);

  hipMemsetAsync(d_out, 0, (size_t)B_*OUT_*sizeof(float), stream);
  hipLaunchKernelGGL(convert_kernel, dim3(4096), dim3(256), 0, stream, x, W1, W2, xb, w1b, w2b);
  hipLaunchKernelGGL(gate_kernel, dim3(B_/64), dim3(256), 0, stream, u, xb, dd, gW, gb, gw);
  hipLaunchKernelGGL(moe_kernel, dim3(B_/128, 4), dim3(256), 0, stream, xb, w1b, w2b, gw, b1, b2, out);
  (void)in_sizes; (void)n_in; (void)out_size; (void)ws_size;
}